// Round 14
// baseline (946.356 us; speedup 1.0000x reference)
//
#include <hip/hip_runtime.h>
#include <hip/hip_bf16.h>
#include <hip/hip_fp16.h>
#include <math.h>

#define N_NODES 100000
#define N_EDGES 1600000
#define N_GRAPHS 1024
#define NB_SCAN ((N_NODES + 255) / 256)   // 391
#define NODES_PER_CHUNK 25000             // layer-1 chunks (4)
#define CHUNK_EDGE_CAP 450000             // +90 sigma margin
#define AGG2_NODES_PER_CHUNK 33334        // layer-2 chunks (3)
#define AGG2_EDGE_CAP 800000              // 51.2MB / 64B per edge; +447 sigma margin

typedef _Float16 f16x8 __attribute__((ext_vector_type(8)));
typedef float f32x4 __attribute__((ext_vector_type(4)));

static __device__ __forceinline__ float bf2f(ushort u) {
    return __uint_as_float(((unsigned)u) << 16);
}
static __device__ __forceinline__ ushort f2bf(float f) {
    unsigned x = __float_as_uint(f);
    return (ushort)((x + 0x7fffu + ((x >> 16) & 1u)) >> 16);   // RNE
}

// ---------------- x -> fp16 (streaming) ----------------
__global__ __launch_bounds__(256) void conv_x(const float* __restrict__ x,
                                              __half* __restrict__ xh) {
    int i = blockIdx.x * blockDim.x + threadIdx.x;   // one thread per 8 elems; exact
    const float4* src = (const float4*)x;
    float4 a = src[2 * i], b = src[2 * i + 1];
    __half2 h0 = __floats2half2_rn(a.x, a.y);
    __half2 h1 = __floats2half2_rn(a.z, a.w);
    __half2 h2 = __floats2half2_rn(b.x, b.y);
    __half2 h3 = __floats2half2_rn(b.z, b.w);
    uint4 o = make_uint4(*(uint*)&h0, *(uint*)&h1, *(uint*)&h2, *(uint*)&h3);
    ((uint4*)xh)[i] = o;
}

// ---------------- W -> fp16 in B-fragment order ----------------
__global__ __launch_bounds__(256) void prepack_W(const float* __restrict__ Wq,
        const float* __restrict__ Wk, const float* __restrict__ Wv,
        const float* __restrict__ Ws, __half* __restrict__ Bpack) {
    int tid = blockIdx.x * 256 + threadIdx.x;
    if (tid >= 4 * 4 * 4 * 64) return;
    int lane = tid & 63, nt = (tid >> 6) & 3, kt = (tid >> 8) & 3, w = (tid >> 10) & 3;
    const float* W = (w == 0) ? Wq : (w == 1) ? Wk : (w == 2) ? Wv : Ws;
    int col = nt * 16 + (lane & 15);
    int kbase = kt * 32 + (lane >> 4) * 8;
    __half* dst = Bpack + (size_t)tid * 8;
#pragma unroll
    for (int j = 0; j < 8; ++j) dst[j] = __float2half(W[(kbase + j) * 64 + col]);
}

// ---------------- layer 1 node linear via MFMA ----------------
__global__ __launch_bounds__(256) void node_lin1_mfma(const __half* __restrict__ xh,
        const float* __restrict__ bq, const float* __restrict__ bk,
        const float* __restrict__ bv, const float* __restrict__ bs,
        const __half* __restrict__ Bpack,
        float* __restrict__ q, uint* __restrict__ kvt, float* __restrict__ s) {
    __shared__ _Float16 As[64][136];
    int tid = threadIdx.x;
    int nb = blockIdx.x * 64;
    {
        int row = tid >> 2, seg = tid & 3;
        int nn = nb + row;
        uint4* dst = (uint4*)&As[row][seg * 32];
        if (nn < N_NODES) {
            const uint4* sp = (const uint4*)(xh + (size_t)nn * 128 + seg * 32);
            dst[0] = sp[0]; dst[1] = sp[1]; dst[2] = sp[2]; dst[3] = sp[3];
        } else {
            uint4 z = make_uint4(0, 0, 0, 0);
            dst[0] = z; dst[1] = z; dst[2] = z; dst[3] = z;
        }
    }
    __syncthreads();
    int wv = tid >> 6, lane = tid & 63;
    const f16x8* Bp = (const f16x8*)Bpack;
    f16x8 Bf[4][4];
#pragma unroll
    for (int kt = 0; kt < 4; ++kt)
#pragma unroll
        for (int nt = 0; nt < 4; ++nt)
            Bf[kt][nt] = Bp[((wv * 4 + kt) * 4 + nt) * 64 + lane];
    f32x4 acc[4][4];
#pragma unroll
    for (int mt = 0; mt < 4; ++mt)
#pragma unroll
        for (int nt = 0; nt < 4; ++nt) acc[mt][nt] = (f32x4){0.f, 0.f, 0.f, 0.f};
    int arow = lane & 15, akoff = (lane >> 4) * 8;
#pragma unroll
    for (int kt = 0; kt < 4; ++kt) {
        f16x8 a[4];
#pragma unroll
        for (int mt = 0; mt < 4; ++mt)
            a[mt] = *(const f16x8*)&As[mt * 16 + arow][kt * 32 + akoff];
#pragma unroll
        for (int mt = 0; mt < 4; ++mt)
#pragma unroll
            for (int nt = 0; nt < 4; ++nt)
                acc[mt][nt] = __builtin_amdgcn_mfma_f32_16x16x32_f16(
                    a[mt], Bf[kt][nt], acc[mt][nt], 0, 0, 0);
    }
    const float* bvec = (wv == 0) ? bq : (wv == 1) ? bk : (wv == 2) ? bv : bs;
    int colw = lane & 15;
    int rgrp = (lane >> 4) * 4;
#pragma unroll
    for (int nt = 0; nt < 4; ++nt) {
        float bias = bvec[nt * 16 + colw];
        int col = nt * 16 + colw;
#pragma unroll
        for (int mt = 0; mt < 4; ++mt) {
#pragma unroll
            for (int r = 0; r < 4; ++r) {
                int node = nb + mt * 16 + rgrp + r;
                if (node >= N_NODES) continue;
                float val = acc[mt][nt][r] + bias;
                if (wv == 0)      q[(size_t)node * 64 + col] = val;
                else if (wv == 1) ((ushort*)kvt)[((size_t)node * 64 + col) * 2]     = f2bf(val);
                else if (wv == 2) ((ushort*)kvt)[((size_t)node * 64 + col) * 2 + 1] = f2bf(val);
                else              s[(size_t)node * 64 + col] = val;
            }
        }
    }
}

// ---------------- layer 2: node linear (64 -> 16) x4 ----------------
__global__ __launch_bounds__(256) void node_lin2(const float* __restrict__ h,
                          const float* __restrict__ Wq, const float* __restrict__ bq,
                          const float* __restrict__ Wk, const float* __restrict__ bk,
                          const float* __restrict__ Wv, const float* __restrict__ bv,
                          const float* __restrict__ Ws, const float* __restrict__ bs,
                          float* __restrict__ q, uint* __restrict__ kvt,
                          float* __restrict__ s) {
    __shared__ float hs[32][65];
    int tid = threadIdx.x;
    int nb = blockIdx.x * 32;
    for (int i = tid; i < 32 * 64; i += 256) {
        int nn = nb + (i >> 6);
        hs[i >> 6][i & 63] = (nn < N_NODES) ? h[(size_t)nb * 64 + i] : 0.f;
    }
    __syncthreads();
    int w = tid >> 6, t = tid & 63, g = t >> 4, c = t & 15;
    const float* W = (w == 0) ? Wq : (w == 1) ? Wk : (w == 2) ? Wv : Ws;
    const float* b = (w == 0) ? bq : (w == 1) ? bk : (w == 2) ? bv : bs;
    float acc[8];
#pragma unroll
    for (int n = 0; n < 8; ++n) acc[n] = 0.f;
#pragma unroll 4
    for (int j = 0; j < 64; ++j) {
        float wv = W[j * 16 + c];
#pragma unroll
        for (int n = 0; n < 8; ++n) acc[n] += hs[g * 8 + n][j] * wv;
    }
    float bb = b[c];
#pragma unroll
    for (int n = 0; n < 8; ++n) {
        int nn = nb + g * 8 + n;
        if (nn >= N_NODES) break;
        float r = acc[n] + bb;
        if (w == 0)      q[(size_t)nn * 16 + c] = r;
        else if (w == 1) ((ushort*)kvt)[((size_t)nn * 16 + c) * 2]     = f2bf(r);
        else if (w == 2) ((ushort*)kvt)[((size_t)nn * 16 + c) * 2 + 1] = f2bf(r);
        else             s[(size_t)nn * 16 + c] = r;
    }
}

// ---------------- CSR build: histogram -> scan -> scatter ----------------
__global__ void hist_kernel(const int* __restrict__ ei, int* __restrict__ deg) {
    int e = blockIdx.x * blockDim.x + threadIdx.x;
    if (e < N_EDGES) atomicAdd(deg + ei[N_EDGES + e], 1);
}

__global__ __launch_bounds__(256) void scan_block(const int* __restrict__ deg,
        int* __restrict__ rowptr, int* __restrict__ bsum) {
    __shared__ int sd[256];
    int i = blockIdx.x * 256 + threadIdx.x;
    int v = (i < N_NODES) ? deg[i] : 0;
    sd[threadIdx.x] = v;
    __syncthreads();
    for (int off = 1; off < 256; off <<= 1) {
        int add = (threadIdx.x >= off) ? sd[threadIdx.x - off] : 0;
        __syncthreads();
        sd[threadIdx.x] += add;
        __syncthreads();
    }
    if (i < N_NODES) rowptr[i] = sd[threadIdx.x] - v;   // exclusive within block
    if (threadIdx.x == 255) bsum[blockIdx.x] = sd[255];
}

__global__ __launch_bounds__(512) void scan_bsum(int* __restrict__ bsum) {
    __shared__ int sd[512];
    int t = threadIdx.x;
    int v = (t < NB_SCAN) ? bsum[t] : 0;
    sd[t] = v;
    __syncthreads();
    for (int off = 1; off < 512; off <<= 1) {
        int add = (t >= off) ? sd[t - off] : 0;
        __syncthreads();
        sd[t] += add;
        __syncthreads();
    }
    if (t < NB_SCAN) bsum[t] = sd[t] - v;               // exclusive
}

__global__ void scan_add(int* __restrict__ rowptr, int* __restrict__ cursor,
                         const int* __restrict__ bsum) {
    int i = blockIdx.x * blockDim.x + threadIdx.x;
    if (i < N_NODES) {
        int r = rowptr[i] + bsum[i >> 8];
        rowptr[i] = r;
        cursor[i] = r;
    }
    if (i == 0) rowptr[N_NODES] = N_EDGES;
}

__global__ void scatter_kernel(const int* __restrict__ ei, int* __restrict__ cursor,
                               int* __restrict__ srcs, int* __restrict__ eids) {
    int e = blockIdx.x * blockDim.x + threadIdx.x;
    if (e >= N_EDGES) return;
    int d = ei[N_EDGES + e];
    int pos = atomicAdd(cursor + d, 1);
    srcs[pos] = ei[e];
    eids[pos] = e;
}

// ------- fused edge MLP: e1 (64ch, chunk-local) + e2 (16ch, global), staged -------
__global__ __launch_bounds__(256) void edge_mlp1(const int* __restrict__ eids,
        const int* __restrict__ rowptr, int n0, int n1,
        const float* __restrict__ ea, const float* __restrict__ We1,
        const float* __restrict__ We2,
        ushort* __restrict__ ep1, ushort* __restrict__ ep2) {
    __shared__ float ea_s[64][36];
    int pbeg = rowptr[n0], pend = rowptr[n1];
    int base = pbeg + blockIdx.x * 64;
    if (base >= pend) return;
    int nedges = pend - base; if (nedges > 64) nedges = 64;
    int tid = threadIdx.x;
    int e4 = tid >> 2, r = tid & 3;
    if (e4 < nedges) {
        int eid = eids[base + e4];
        const float4* src = (const float4*)(ea + (size_t)eid * 32);
        ((float4*)ea_s[e4])[r * 2]     = src[r * 2];
        ((float4*)ea_s[e4])[r * 2 + 1] = src[r * 2 + 1];
    }
    __syncthreads();
    int w = tid >> 6, t = tid & 63;
    int c2 = t & 15, j0 = (t >> 4) * 8;
    float we[32];
#pragma unroll
    for (int j = 0; j < 32; ++j) we[j] = We1[j * 64 + t];
    float we2p[8];
#pragma unroll
    for (int i = 0; i < 8; ++i) we2p[i] = We2[(j0 + i) * 16 + c2];
    int e0 = w * 16;
    int ecnt = nedges - e0; if (ecnt > 16) ecnt = 16;
    for (int e = 0; e < ecnt; ++e) {
        const float4* row = (const float4*)ea_s[e0 + e];
        float et = 0.f;
#pragma unroll
        for (int r2 = 0; r2 < 8; ++r2) {
            float4 f = row[r2];
            et += f.x * we[4*r2] + f.y * we[4*r2+1] + f.z * we[4*r2+2] + f.w * we[4*r2+3];
        }
        ep1[(size_t)(base - pbeg + e0 + e) * 64 + t] = f2bf(et);
        const float* rowf = ea_s[e0 + e] + j0;
        float p2 = rowf[0] * we2p[0] + rowf[1] * we2p[1] + rowf[2] * we2p[2]
                 + rowf[3] * we2p[3] + rowf[4] * we2p[4] + rowf[5] * we2p[5]
                 + rowf[6] * we2p[6] + rowf[7] * we2p[7];
        p2 += __shfl_xor(p2, 16, 64);
        p2 += __shfl_xor(p2, 32, 64);
        if (t < 16) ep2[(size_t)(base + e0 + e) * 16 + t] = f2bf(p2);
    }
}

// ---------------- layer 1: per-dst attention, 16-lane groups, 2-edge ILP ----
__global__ __launch_bounds__(256) void agg_l1(const int* __restrict__ srcs,
        const int* __restrict__ rowptr, const ushort* __restrict__ ep1,
        const float* __restrict__ q, const uint* __restrict__ kvt,
        float* __restrict__ h, int n0, int n1) {
    int w = threadIdx.x >> 6, t = threadIdx.x & 63;
    int n = n0 + blockIdx.x * 4 + w;
    if (n >= n1) return;
    int g = t >> 4, c = t & 15;
    int pbeg = rowptr[n0];
    float4 q4 = ((const float4*)(q + (size_t)n * 64))[c];
    int beg = rowptr[n], end = rowptr[n + 1];
    float den = 0.f;
    float ax = 0.f, ay = 0.f, az = 0.f, aw = 0.f;
    int idx = beg + g;
    for (; idx + 4 < end; idx += 8) {
        int sA = srcs[idx], sB = srcs[idx + 4];
        uint4 kvA = ((const uint4*)(kvt + (size_t)sA * 64))[c];
        uint4 kvB = ((const uint4*)(kvt + (size_t)sB * 64))[c];
        ushort4 eA = ((const ushort4*)(ep1 + (size_t)(idx - pbeg) * 64))[c];
        ushort4 eB = ((const ushort4*)(ep1 + (size_t)(idx + 4 - pbeg) * 64))[c];
        float eA0 = bf2f(eA.x), eA1 = bf2f(eA.y), eA2 = bf2f(eA.z), eA3 = bf2f(eA.w);
        float eB0 = bf2f(eB.x), eB1 = bf2f(eB.y), eB2 = bf2f(eB.z), eB3 = bf2f(eB.w);
        float kA0 = bf2f((ushort)kvA.x), vA0 = bf2f((ushort)(kvA.x >> 16));
        float kA1 = bf2f((ushort)kvA.y), vA1 = bf2f((ushort)(kvA.y >> 16));
        float kA2 = bf2f((ushort)kvA.z), vA2 = bf2f((ushort)(kvA.z >> 16));
        float kA3 = bf2f((ushort)kvA.w), vA3 = bf2f((ushort)(kvA.w >> 16));
        float kB0 = bf2f((ushort)kvB.x), vB0 = bf2f((ushort)(kvB.x >> 16));
        float kB1 = bf2f((ushort)kvB.y), vB1 = bf2f((ushort)(kvB.y >> 16));
        float kB2 = bf2f((ushort)kvB.z), vB2 = bf2f((ushort)(kvB.z >> 16));
        float kB3 = bf2f((ushort)kvB.w), vB3 = bf2f((ushort)(kvB.w >> 16));
        float pA = q4.x * (kA0 + eA0) + q4.y * (kA1 + eA1)
                 + q4.z * (kA2 + eA2) + q4.w * (kA3 + eA3);
        float pB = q4.x * (kB0 + eB0) + q4.y * (kB1 + eB1)
                 + q4.z * (kB2 + eB2) + q4.w * (kB3 + eB3);
        pA += __shfl_xor(pA, 1, 64); pB += __shfl_xor(pB, 1, 64);
        pA += __shfl_xor(pA, 2, 64); pB += __shfl_xor(pB, 2, 64);
        pA += __shfl_xor(pA, 4, 64); pB += __shfl_xor(pB, 4, 64);
        pA += __shfl_xor(pA, 8, 64); pB += __shfl_xor(pB, 8, 64);
        float aA = __expf(pA * 0.125f), aB = __expf(pB * 0.125f);
        den += aA + aB;
        ax += aA * (vA0 + eA0) + aB * (vB0 + eB0);
        ay += aA * (vA1 + eA1) + aB * (vB1 + eB1);
        az += aA * (vA2 + eA2) + aB * (vB2 + eB2);
        aw += aA * (vA3 + eA3) + aB * (vB3 + eB3);
    }
    if (idx < end) {
        int s = srcs[idx];
        uint4 kv4 = ((const uint4*)(kvt + (size_t)s * 64))[c];
        ushort4 e4 = ((const ushort4*)(ep1 + (size_t)(idx - pbeg) * 64))[c];
        float e0 = bf2f(e4.x), e1 = bf2f(e4.y), e2 = bf2f(e4.z), e3 = bf2f(e4.w);
        float k0 = bf2f((ushort)kv4.x), v0 = bf2f((ushort)(kv4.x >> 16));
        float k1 = bf2f((ushort)kv4.y), v1 = bf2f((ushort)(kv4.y >> 16));
        float k2 = bf2f((ushort)kv4.z), v2 = bf2f((ushort)(kv4.z >> 16));
        float k3 = bf2f((ushort)kv4.w), v3 = bf2f((ushort)(kv4.w >> 16));
        float p = q4.x * (k0 + e0) + q4.y * (k1 + e1) + q4.z * (k2 + e2) + q4.w * (k3 + e3);
        p += __shfl_xor(p, 1, 64);
        p += __shfl_xor(p, 2, 64);
        p += __shfl_xor(p, 4, 64);
        p += __shfl_xor(p, 8, 64);
        float a = __expf(p * 0.125f);
        den += a;
        ax += a * (v0 + e0); ay += a * (v1 + e1);
        az += a * (v2 + e2); aw += a * (v3 + e3);
    }
    den += __shfl_xor(den, 16, 64); den += __shfl_xor(den, 32, 64);
    ax += __shfl_xor(ax, 16, 64);   ax += __shfl_xor(ax, 32, 64);
    ay += __shfl_xor(ay, 16, 64);   ay += __shfl_xor(ay, 32, 64);
    az += __shfl_xor(az, 16, 64);   az += __shfl_xor(az, 32, 64);
    aw += __shfl_xor(aw, 16, 64);   aw += __shfl_xor(aw, 32, 64);
    if (g == 0) {
        float4* hp = (float4*)(h + (size_t)n * 64) + c;
        float4 hv = *hp;
        float d = den + 1e-16f;
        float4 o;
        o.x = ax / d + hv.x; o.x = o.x > 0.f ? o.x : 0.f;
        o.y = ay / d + hv.y; o.y = o.y > 0.f ? o.y : 0.f;
        o.z = az / d + hv.z; o.z = o.z > 0.f ? o.z : 0.f;
        o.w = aw / d + hv.w; o.w = o.w > 0.f ? o.w : 0.f;
        *hp = o;
    }
}

// ---------------- kv2 pre-gather into CSR order (chunk-local) ----------------
// one thread per (edge, channel): fully independent loads, no serial chains
__global__ __launch_bounds__(256) void gather_kv2(const int* __restrict__ srcs,
        const int* __restrict__ rowptr, const uint* __restrict__ kvt2,
        uint* __restrict__ kv2e, int n0, int n1) {
    int pbeg = rowptr[n0], pend = rowptr[n1];
    int nloc = pend - pbeg;
    if (nloc > AGG2_EDGE_CAP) nloc = AGG2_EDGE_CAP;
    int i = blockIdx.x * 256 + threadIdx.x;
    if (i >= nloc * 16) return;
    int e = i >> 4, c = i & 15;
    kv2e[i] = kvt2[(size_t)srcs[pbeg + e] * 16 + c];
}

// ---------------- layer 2: per-dst attention + mean-pool, all-sequential ------
// chunked; groups take contiguous 4-edge blocks; kv2e chunk-local, ep2 global
__global__ __launch_bounds__(256) void agg_l2(const int* __restrict__ rowptr,
        const uint* __restrict__ kv2e, const ushort* __restrict__ ep2,
        const float* __restrict__ q, const float* __restrict__ skip,
        const int* __restrict__ batch, float* __restrict__ sums,
        float* __restrict__ cnt, int n0, int n1) {
    int w = threadIdx.x >> 6, t = threadIdx.x & 63;
    int n = n0 + blockIdx.x * 4 + w;
    if (n >= n1) return;
    int g = t >> 4, c = t & 15;
    int pbeg = rowptr[n0];
    float qv = q[(size_t)n * 16 + c];
    int beg = rowptr[n], end = rowptr[n + 1];
    int deg = end - beg;
    int nfull = deg & ~15;
    float den = 0.f, acc = 0.f;
    for (int b = 0; b < nfull; b += 16) {
        int e0 = beg + b + g * 4;            // 4 consecutive edges for this group
        int l0 = e0 - pbeg;
        uint kvA = kv2e[(size_t)l0 * 16 + c];
        uint kvB = kv2e[(size_t)(l0 + 1) * 16 + c];
        uint kvC = kv2e[(size_t)(l0 + 2) * 16 + c];
        uint kvD = kv2e[(size_t)(l0 + 3) * 16 + c];
        float eA = bf2f(ep2[(size_t)e0 * 16 + c]);
        float eB = bf2f(ep2[(size_t)(e0 + 1) * 16 + c]);
        float eC = bf2f(ep2[(size_t)(e0 + 2) * 16 + c]);
        float eD = bf2f(ep2[(size_t)(e0 + 3) * 16 + c]);
        float pA = qv * (bf2f((ushort)kvA) + eA);
        float pB = qv * (bf2f((ushort)kvB) + eB);
        float pC = qv * (bf2f((ushort)kvC) + eC);
        float pD = qv * (bf2f((ushort)kvD) + eD);
        pA += __shfl_xor(pA, 8, 64); pB += __shfl_xor(pB, 8, 64);
        pC += __shfl_xor(pC, 8, 64); pD += __shfl_xor(pD, 8, 64);
        pA += __shfl_xor(pA, 4, 64); pB += __shfl_xor(pB, 4, 64);
        pC += __shfl_xor(pC, 4, 64); pD += __shfl_xor(pD, 4, 64);
        pA += __shfl_xor(pA, 2, 64); pB += __shfl_xor(pB, 2, 64);
        pC += __shfl_xor(pC, 2, 64); pD += __shfl_xor(pD, 2, 64);
        pA += __shfl_xor(pA, 1, 64); pB += __shfl_xor(pB, 1, 64);
        pC += __shfl_xor(pC, 1, 64); pD += __shfl_xor(pD, 1, 64);
        float aA = __expf(pA * 0.25f), aB = __expf(pB * 0.25f);
        float aC = __expf(pC * 0.25f), aD = __expf(pD * 0.25f);
        den += (aA + aB) + (aC + aD);
        acc += aA * (bf2f((ushort)(kvA >> 16)) + eA)
             + aB * (bf2f((ushort)(kvB >> 16)) + eB)
             + aC * (bf2f((ushort)(kvC >> 16)) + eC)
             + aD * (bf2f((ushort)(kvD >> 16)) + eD);
    }
    // tail (<16 edges): strided singles
    for (int idx = beg + nfull + g; idx < end; idx += 4) {
        uint kvp = kv2e[(size_t)(idx - pbeg) * 16 + c];
        float e2 = bf2f(ep2[(size_t)idx * 16 + c]);
        float p = qv * (bf2f((ushort)kvp) + e2);
        p += __shfl_xor(p, 8, 64);
        p += __shfl_xor(p, 4, 64);
        p += __shfl_xor(p, 2, 64);
        p += __shfl_xor(p, 1, 64);
        float a = __expf(p * 0.25f);
        den += a;
        acc += a * (bf2f((ushort)(kvp >> 16)) + e2);
    }
    den += __shfl_xor(den, 16, 64);
    den += __shfl_xor(den, 32, 64);
    acc += __shfl_xor(acc, 16, 64);
    acc += __shfl_xor(acc, 32, 64);
    if (t < 16) {
        float r2 = acc / (den + 1e-16f) + skip[(size_t)n * 16 + c];
        r2 = r2 > 0.f ? r2 : 0.f;
        int gb = batch[n];
        atomicAdd(sums + gb * 16 + c, r2);
        if (c == 0) atomicAdd(cnt + gb, 1.0f);
    }
}

// ---------------- final fc + sigmoid ----------------
__global__ void final_fc(const float* __restrict__ sums, const float* __restrict__ cnt,
                         const float* __restrict__ Wf, const float* __restrict__ bf,
                         float* __restrict__ out) {
    int g = blockIdx.x * blockDim.x + threadIdx.x;
    if (g >= N_GRAPHS) return;
    float cc = cnt[g];
    cc = cc > 1.f ? cc : 1.f;
    float acc = bf[0];
#pragma unroll
    for (int c = 0; c < 16; ++c) acc += (sums[g * 16 + c] / cc) * Wf[c];
    out[g] = 1.f / (1.f + expf(-acc));
}

extern "C" void kernel_launch(void* const* d_in, const int* in_sizes, int n_in,
                              void* d_out, int out_size, void* d_ws, size_t ws_size,
                              hipStream_t stream) {
    const float* x    = (const float*)d_in[0];
    const float* ea   = (const float*)d_in[1];
    const float* Wq1  = (const float*)d_in[2];
    const float* bq1  = (const float*)d_in[3];
    const float* Wk1  = (const float*)d_in[4];
    const float* bk1  = (const float*)d_in[5];
    const float* Wv1  = (const float*)d_in[6];
    const float* bv1  = (const float*)d_in[7];
    const float* We1  = (const float*)d_in[8];
    const float* Ws1  = (const float*)d_in[9];
    const float* bs1  = (const float*)d_in[10];
    const float* Wq2  = (const float*)d_in[11];
    const float* bq2  = (const float*)d_in[12];
    const float* Wk2  = (const float*)d_in[13];
    const float* bk2  = (const float*)d_in[14];
    const float* Wv2  = (const float*)d_in[15];
    const float* bv2  = (const float*)d_in[16];
    const float* We2  = (const float*)d_in[17];
    const float* Ws2  = (const float*)d_in[18];
    const float* bs2  = (const float*)d_in[19];
    const float* Wf   = (const float*)d_in[20];
    const float* bf   = (const float*)d_in[21];
    const int*   ei   = (const int*)d_in[22];
    const int*   batch= (const int*)d_in[23];
    float* out = (float*)d_out;

    // -------- workspace layout (~216 MB + 64 KB) --------
    float* ws = (float*)d_ws;
    size_t off = 0;
    float* q1    = ws + off;          off += (size_t)N_NODES * 64;
    uint* kvt1   = (uint*)(ws + off); off += (size_t)N_NODES * 64;
    float* s1    = ws + off;          off += (size_t)N_NODES * 64;   // skip -> h1
    float* q2    = ws + off;          off += (size_t)N_NODES * 16;
    uint* kvt2   = (uint*)(ws + off); off += (size_t)N_NODES * 16;
    float* s2    = ws + off;          off += (size_t)N_NODES * 16;
    int* srcs    = (int*)(ws + off);  off += N_EDGES;
    int* eids    = (int*)(ws + off);  off += N_EDGES;
    ushort* ep1  = (ushort*)(ws + off); off += (size_t)CHUNK_EDGE_CAP * 32;  // chunk-local
    ushort* ep2  = (ushort*)(ws + off); off += (size_t)N_EDGES * 8;          // global
    int* rowptr  = (int*)(ws + off);  off += N_NODES + 2;
    int* cursor  = (int*)(ws + off);  off += N_NODES;
    int* bsum    = (int*)(ws + off);  off += 512;
    // ---- contiguous zero block ----
    float* zerop = ws + off;
    int*   deg   = (int*)(ws + off);  off += N_NODES;
    float* sums  = ws + off;          off += (size_t)N_GRAPHS * 16;
    float* cnt   = ws + off;          off += N_GRAPHS;
    size_t zero_bytes = ((size_t)N_NODES + N_GRAPHS * 16 + N_GRAPHS) * sizeof(float);
    off = (off + 3) & ~(size_t)3;
    __half* Bpack = (__half*)(ws + off); off += 16384;   // 64 KB
    // aliases: xh (fp16 x) on ep1 (dead before edge_mlp1);
    //          kv2e (layer-2 gathered kv) on q1+kvt1 (dead after agg_l1)
    __half* xh = (__half*)ep1;
    uint* kv2e = (uint*)q1;            // capacity: 12.8M uints = AGG2_EDGE_CAP*16

    hipMemsetAsync(zerop, 0, zero_bytes, stream);

    // -------- prep: x->fp16, W->fp16 fragment pack --------
    conv_x<<<6250, 256, 0, stream>>>(x, xh);
    prepack_W<<<16, 256, 0, stream>>>(Wq1, Wk1, Wv1, Ws1, Bpack);

    // -------- CSR build (shared by both layers) --------
    hist_kernel<<<(N_EDGES + 255) / 256, 256, 0, stream>>>(ei, deg);
    scan_block<<<NB_SCAN, 256, 0, stream>>>(deg, rowptr, bsum);
    scan_bsum<<<1, 512, 0, stream>>>(bsum);
    scan_add<<<NB_SCAN, 256, 0, stream>>>(rowptr, cursor, bsum);
    scatter_kernel<<<(N_EDGES + 255) / 256, 256, 0, stream>>>(ei, cursor, srcs, eids);

    // -------- layer 1 node linear (MFMA) --------
    node_lin1_mfma<<<(N_NODES + 63) / 64, 256, 0, stream>>>(xh, bq1, bk1, bv1, bs1,
                                                            Bpack, q1, kvt1, s1);

    // -------- layer 1 (chunked: staged fused edge MLP -> aggregation) --------
    int mlp_blocks = (CHUNK_EDGE_CAP + 63) / 64;
    for (int c = 0; c < 4; ++c) {
        int n0 = c * NODES_PER_CHUNK;
        int n1 = (c + 1) * NODES_PER_CHUNK;
        if (n1 > N_NODES) n1 = N_NODES;
        edge_mlp1<<<mlp_blocks, 256, 0, stream>>>(eids, rowptr, n0, n1, ea,
                                                  We1, We2, ep1, ep2);
        agg_l1<<<(NODES_PER_CHUNK + 3) / 4, 256, 0, stream>>>(srcs, rowptr, ep1,
                                                              q1, kvt1, s1, n0, n1);
    }

    // -------- layer 2 node linear --------
    node_lin2<<<(N_NODES + 31) / 32, 256, 0, stream>>>(s1, Wq2, bq2, Wk2, bk2, Wv2, bv2,
                                                       Ws2, bs2, q2, kvt2, s2);

    // -------- layer 2 (chunked: pre-gather kv -> all-sequential aggregation) ----
    int gth_blocks = (AGG2_EDGE_CAP * 16 + 255) / 256;
    for (int c = 0; c < 3; ++c) {
        int n0 = c * AGG2_NODES_PER_CHUNK;
        int n1 = (c + 1) * AGG2_NODES_PER_CHUNK;
        if (n1 > N_NODES) n1 = N_NODES;
        gather_kv2<<<gth_blocks, 256, 0, stream>>>(srcs, rowptr, kvt2, kv2e, n0, n1);
        agg_l2<<<(AGG2_NODES_PER_CHUNK + 3) / 4, 256, 0, stream>>>(rowptr, kv2e, ep2,
                                                q2, s2, batch, sums, cnt, n0, n1);
    }

    // -------- final fc --------
    final_fc<<<(N_GRAPHS + 255) / 256, 256, 0, stream>>>(sums, cnt, Wf, bf, out);
}

// Round 15
// 860.795 us; speedup vs baseline: 1.0994x; 1.0994x over previous
//
#include <hip/hip_runtime.h>
#include <hip/hip_bf16.h>
#include <hip/hip_fp16.h>
#include <math.h>

#define N_NODES 100000
#define N_EDGES 1600000
#define N_GRAPHS 1024
#define NB_SCAN ((N_NODES + 255) / 256)   // 391
#define NODES_PER_CHUNK 25000             // layer-1 chunks (4)
#define CHUNK_EDGE_CAP 450000             // +90 sigma margin

typedef _Float16 f16x8 __attribute__((ext_vector_type(8)));
typedef float f32x4 __attribute__((ext_vector_type(4)));

static __device__ __forceinline__ float bf2f(ushort u) {
    return __uint_as_float(((unsigned)u) << 16);
}
static __device__ __forceinline__ ushort f2bf(float f) {
    unsigned x = __float_as_uint(f);
    return (ushort)((x + 0x7fffu + ((x >> 16) & 1u)) >> 16);   // RNE
}

// ---------------- x -> fp16 (streaming) ----------------
__global__ __launch_bounds__(256) void conv_x(const float* __restrict__ x,
                                              __half* __restrict__ xh) {
    int i = blockIdx.x * blockDim.x + threadIdx.x;
    const float4* src = (const float4*)x;
    float4 a = src[2 * i], b = src[2 * i + 1];
    __half2 h0 = __floats2half2_rn(a.x, a.y);
    __half2 h1 = __floats2half2_rn(a.z, a.w);
    __half2 h2 = __floats2half2_rn(b.x, b.y);
    __half2 h3 = __floats2half2_rn(b.z, b.w);
    uint4 o = make_uint4(*(uint*)&h0, *(uint*)&h1, *(uint*)&h2, *(uint*)&h3);
    ((uint4*)xh)[i] = o;
}

// ---------------- W -> fp16 in B-fragment order ----------------
__global__ __launch_bounds__(256) void prepack_W(const float* __restrict__ Wq,
        const float* __restrict__ Wk, const float* __restrict__ Wv,
        const float* __restrict__ Ws, __half* __restrict__ Bpack) {
    int tid = blockIdx.x * 256 + threadIdx.x;
    if (tid >= 4 * 4 * 4 * 64) return;
    int lane = tid & 63, nt = (tid >> 6) & 3, kt = (tid >> 8) & 3, w = (tid >> 10) & 3;
    const float* W = (w == 0) ? Wq : (w == 1) ? Wk : (w == 2) ? Wv : Ws;
    int col = nt * 16 + (lane & 15);
    int kbase = kt * 32 + (lane >> 4) * 8;
    __half* dst = Bpack + (size_t)tid * 8;
#pragma unroll
    for (int j = 0; j < 8; ++j) dst[j] = __float2half(W[(kbase + j) * 64 + col]);
}

// ---------------- layer 1 node linear via MFMA ----------------
__global__ __launch_bounds__(256) void node_lin1_mfma(const __half* __restrict__ xh,
        const float* __restrict__ bq, const float* __restrict__ bk,
        const float* __restrict__ bv, const float* __restrict__ bs,
        const __half* __restrict__ Bpack,
        float* __restrict__ q, uint* __restrict__ kvt, float* __restrict__ s) {
    __shared__ _Float16 As[64][136];
    int tid = threadIdx.x;
    int nb = blockIdx.x * 64;
    {
        int row = tid >> 2, seg = tid & 3;
        int nn = nb + row;
        uint4* dst = (uint4*)&As[row][seg * 32];
        if (nn < N_NODES) {
            const uint4* sp = (const uint4*)(xh + (size_t)nn * 128 + seg * 32);
            dst[0] = sp[0]; dst[1] = sp[1]; dst[2] = sp[2]; dst[3] = sp[3];
        } else {
            uint4 z = make_uint4(0, 0, 0, 0);
            dst[0] = z; dst[1] = z; dst[2] = z; dst[3] = z;
        }
    }
    __syncthreads();
    int wv = tid >> 6, lane = tid & 63;
    const f16x8* Bp = (const f16x8*)Bpack;
    f16x8 Bf[4][4];
#pragma unroll
    for (int kt = 0; kt < 4; ++kt)
#pragma unroll
        for (int nt = 0; nt < 4; ++nt)
            Bf[kt][nt] = Bp[((wv * 4 + kt) * 4 + nt) * 64 + lane];
    f32x4 acc[4][4];
#pragma unroll
    for (int mt = 0; mt < 4; ++mt)
#pragma unroll
        for (int nt = 0; nt < 4; ++nt) acc[mt][nt] = (f32x4){0.f, 0.f, 0.f, 0.f};
    int arow = lane & 15, akoff = (lane >> 4) * 8;
#pragma unroll
    for (int kt = 0; kt < 4; ++kt) {
        f16x8 a[4];
#pragma unroll
        for (int mt = 0; mt < 4; ++mt)
            a[mt] = *(const f16x8*)&As[mt * 16 + arow][kt * 32 + akoff];
#pragma unroll
        for (int mt = 0; mt < 4; ++mt)
#pragma unroll
            for (int nt = 0; nt < 4; ++nt)
                acc[mt][nt] = __builtin_amdgcn_mfma_f32_16x16x32_f16(
                    a[mt], Bf[kt][nt], acc[mt][nt], 0, 0, 0);
    }
    const float* bvec = (wv == 0) ? bq : (wv == 1) ? bk : (wv == 2) ? bv : bs;
    int colw = lane & 15;
    int rgrp = (lane >> 4) * 4;
#pragma unroll
    for (int nt = 0; nt < 4; ++nt) {
        float bias = bvec[nt * 16 + colw];
        int col = nt * 16 + colw;
#pragma unroll
        for (int mt = 0; mt < 4; ++mt) {
#pragma unroll
            for (int r = 0; r < 4; ++r) {
                int node = nb + mt * 16 + rgrp + r;
                if (node >= N_NODES) continue;
                float val = acc[mt][nt][r] + bias;
                if (wv == 0)      q[(size_t)node * 64 + col] = val;
                else if (wv == 1) ((ushort*)kvt)[((size_t)node * 64 + col) * 2]     = f2bf(val);
                else if (wv == 2) ((ushort*)kvt)[((size_t)node * 64 + col) * 2 + 1] = f2bf(val);
                else              s[(size_t)node * 64 + col] = val;
            }
        }
    }
}

// ---------------- layer 2: node linear (64 -> 16) x4 ----------------
__global__ __launch_bounds__(256) void node_lin2(const float* __restrict__ h,
                          const float* __restrict__ Wq, const float* __restrict__ bq,
                          const float* __restrict__ Wk, const float* __restrict__ bk,
                          const float* __restrict__ Wv, const float* __restrict__ bv,
                          const float* __restrict__ Ws, const float* __restrict__ bs,
                          float* __restrict__ q, uint* __restrict__ kvt,
                          float* __restrict__ s) {
    __shared__ float hs[32][65];
    int tid = threadIdx.x;
    int nb = blockIdx.x * 32;
    for (int i = tid; i < 32 * 64; i += 256) {
        int nn = nb + (i >> 6);
        hs[i >> 6][i & 63] = (nn < N_NODES) ? h[(size_t)nb * 64 + i] : 0.f;
    }
    __syncthreads();
    int w = tid >> 6, t = tid & 63, g = t >> 4, c = t & 15;
    const float* W = (w == 0) ? Wq : (w == 1) ? Wk : (w == 2) ? Wv : Ws;
    const float* b = (w == 0) ? bq : (w == 1) ? bk : (w == 2) ? bv : bs;
    float acc[8];
#pragma unroll
    for (int n = 0; n < 8; ++n) acc[n] = 0.f;
#pragma unroll 4
    for (int j = 0; j < 64; ++j) {
        float wv = W[j * 16 + c];
#pragma unroll
        for (int n = 0; n < 8; ++n) acc[n] += hs[g * 8 + n][j] * wv;
    }
    float bb = b[c];
#pragma unroll
    for (int n = 0; n < 8; ++n) {
        int nn = nb + g * 8 + n;
        if (nn >= N_NODES) break;
        float r = acc[n] + bb;
        if (w == 0)      q[(size_t)nn * 16 + c] = r;
        else if (w == 1) ((ushort*)kvt)[((size_t)nn * 16 + c) * 2]     = f2bf(r);
        else if (w == 2) ((ushort*)kvt)[((size_t)nn * 16 + c) * 2 + 1] = f2bf(r);
        else             s[(size_t)nn * 16 + c] = r;
    }
}

// ---------------- CSR build: histogram -> scan -> scatter ----------------
__global__ void hist_kernel(const int* __restrict__ ei, int* __restrict__ deg) {
    int e = blockIdx.x * blockDim.x + threadIdx.x;
    if (e < N_EDGES) atomicAdd(deg + ei[N_EDGES + e], 1);
}

__global__ __launch_bounds__(256) void scan_block(const int* __restrict__ deg,
        int* __restrict__ rowptr, int* __restrict__ bsum) {
    __shared__ int sd[256];
    int i = blockIdx.x * 256 + threadIdx.x;
    int v = (i < N_NODES) ? deg[i] : 0;
    sd[threadIdx.x] = v;
    __syncthreads();
    for (int off = 1; off < 256; off <<= 1) {
        int add = (threadIdx.x >= off) ? sd[threadIdx.x - off] : 0;
        __syncthreads();
        sd[threadIdx.x] += add;
        __syncthreads();
    }
    if (i < N_NODES) rowptr[i] = sd[threadIdx.x] - v;   // exclusive within block
    if (threadIdx.x == 255) bsum[blockIdx.x] = sd[255];
}

__global__ __launch_bounds__(512) void scan_bsum(int* __restrict__ bsum) {
    __shared__ int sd[512];
    int t = threadIdx.x;
    int v = (t < NB_SCAN) ? bsum[t] : 0;
    sd[t] = v;
    __syncthreads();
    for (int off = 1; off < 512; off <<= 1) {
        int add = (t >= off) ? sd[t - off] : 0;
        __syncthreads();
        sd[t] += add;
        __syncthreads();
    }
    if (t < NB_SCAN) bsum[t] = sd[t] - v;               // exclusive
}

__global__ void scan_add(int* __restrict__ rowptr, int* __restrict__ cursor,
                         const int* __restrict__ bsum) {
    int i = blockIdx.x * blockDim.x + threadIdx.x;
    if (i < N_NODES) {
        int r = rowptr[i] + bsum[i >> 8];
        rowptr[i] = r;
        cursor[i] = r;
    }
    if (i == 0) rowptr[N_NODES] = N_EDGES;
}

__global__ void scatter_kernel(const int* __restrict__ ei, int* __restrict__ cursor,
                               int2* __restrict__ sorted) {
    int e = blockIdx.x * blockDim.x + threadIdx.x;
    if (e >= N_EDGES) return;
    int d = ei[N_EDGES + e];
    int pos = atomicAdd(cursor + d, 1);
    sorted[pos] = make_int2(ei[e], e);   // (src, eid)
}

// ------- fused edge MLP: e1 (64ch, chunk-local) + e2 (16ch, global), staged -------
__global__ __launch_bounds__(256) void edge_mlp1(const int2* __restrict__ sorted,
        const int* __restrict__ rowptr, int n0, int n1,
        const float* __restrict__ ea, const float* __restrict__ We1,
        const float* __restrict__ We2,
        ushort* __restrict__ ep1, ushort* __restrict__ ep2) {
    __shared__ float ea_s[64][36];
    int pbeg = rowptr[n0], pend = rowptr[n1];
    int base = pbeg + blockIdx.x * 64;
    if (base >= pend) return;
    int nedges = pend - base; if (nedges > 64) nedges = 64;
    int tid = threadIdx.x;
    int e4 = tid >> 2, r = tid & 3;
    if (e4 < nedges) {
        int eid = sorted[base + e4].y;
        const float4* src = (const float4*)(ea + (size_t)eid * 32);
        ((float4*)ea_s[e4])[r * 2]     = src[r * 2];
        ((float4*)ea_s[e4])[r * 2 + 1] = src[r * 2 + 1];
    }
    __syncthreads();
    int w = tid >> 6, t = tid & 63;
    int c2 = t & 15, j0 = (t >> 4) * 8;
    float we[32];
#pragma unroll
    for (int j = 0; j < 32; ++j) we[j] = We1[j * 64 + t];
    float we2p[8];
#pragma unroll
    for (int i = 0; i < 8; ++i) we2p[i] = We2[(j0 + i) * 16 + c2];
    int e0 = w * 16;
    int ecnt = nedges - e0; if (ecnt > 16) ecnt = 16;
    for (int e = 0; e < ecnt; ++e) {
        const float4* row = (const float4*)ea_s[e0 + e];
        float et = 0.f;
#pragma unroll
        for (int r2 = 0; r2 < 8; ++r2) {
            float4 f = row[r2];
            et += f.x * we[4*r2] + f.y * we[4*r2+1] + f.z * we[4*r2+2] + f.w * we[4*r2+3];
        }
        ep1[(size_t)(base - pbeg + e0 + e) * 64 + t] = f2bf(et);
        const float* rowf = ea_s[e0 + e] + j0;
        float p2 = rowf[0] * we2p[0] + rowf[1] * we2p[1] + rowf[2] * we2p[2]
                 + rowf[3] * we2p[3] + rowf[4] * we2p[4] + rowf[5] * we2p[5]
                 + rowf[6] * we2p[6] + rowf[7] * we2p[7];
        p2 += __shfl_xor(p2, 16, 64);
        p2 += __shfl_xor(p2, 32, 64);
        if (t < 16) ep2[(size_t)(base + e0 + e) * 16 + t] = f2bf(p2);
    }
}

// ---------------- layer 1: per-dst attention, 16-lane groups, 2-edge ILP ----
__global__ __launch_bounds__(256) void agg_l1(const int2* __restrict__ sorted,
        const int* __restrict__ rowptr, const ushort* __restrict__ ep1,
        const float* __restrict__ q, const uint* __restrict__ kvt,
        float* __restrict__ h, int n0, int n1) {
    int w = threadIdx.x >> 6, t = threadIdx.x & 63;
    int n = n0 + blockIdx.x * 4 + w;
    if (n >= n1) return;
    int g = t >> 4, c = t & 15;
    int pbeg = rowptr[n0];
    float4 q4 = ((const float4*)(q + (size_t)n * 64))[c];
    int beg = rowptr[n], end = rowptr[n + 1];
    float den = 0.f;
    float ax = 0.f, ay = 0.f, az = 0.f, aw = 0.f;
    int idx = beg + g;
    for (; idx + 4 < end; idx += 8) {
        int sA = sorted[idx].x, sB = sorted[idx + 4].x;
        uint4 kvA = ((const uint4*)(kvt + (size_t)sA * 64))[c];
        uint4 kvB = ((const uint4*)(kvt + (size_t)sB * 64))[c];
        ushort4 eA = ((const ushort4*)(ep1 + (size_t)(idx - pbeg) * 64))[c];
        ushort4 eB = ((const ushort4*)(ep1 + (size_t)(idx + 4 - pbeg) * 64))[c];
        float eA0 = bf2f(eA.x), eA1 = bf2f(eA.y), eA2 = bf2f(eA.z), eA3 = bf2f(eA.w);
        float eB0 = bf2f(eB.x), eB1 = bf2f(eB.y), eB2 = bf2f(eB.z), eB3 = bf2f(eB.w);
        float kA0 = bf2f((ushort)kvA.x), vA0 = bf2f((ushort)(kvA.x >> 16));
        float kA1 = bf2f((ushort)kvA.y), vA1 = bf2f((ushort)(kvA.y >> 16));
        float kA2 = bf2f((ushort)kvA.z), vA2 = bf2f((ushort)(kvA.z >> 16));
        float kA3 = bf2f((ushort)kvA.w), vA3 = bf2f((ushort)(kvA.w >> 16));
        float kB0 = bf2f((ushort)kvB.x), vB0 = bf2f((ushort)(kvB.x >> 16));
        float kB1 = bf2f((ushort)kvB.y), vB1 = bf2f((ushort)(kvB.y >> 16));
        float kB2 = bf2f((ushort)kvB.z), vB2 = bf2f((ushort)(kvB.z >> 16));
        float kB3 = bf2f((ushort)kvB.w), vB3 = bf2f((ushort)(kvB.w >> 16));
        float pA = q4.x * (kA0 + eA0) + q4.y * (kA1 + eA1)
                 + q4.z * (kA2 + eA2) + q4.w * (kA3 + eA3);
        float pB = q4.x * (kB0 + eB0) + q4.y * (kB1 + eB1)
                 + q4.z * (kB2 + eB2) + q4.w * (kB3 + eB3);
        pA += __shfl_xor(pA, 1, 64); pB += __shfl_xor(pB, 1, 64);
        pA += __shfl_xor(pA, 2, 64); pB += __shfl_xor(pB, 2, 64);
        pA += __shfl_xor(pA, 4, 64); pB += __shfl_xor(pB, 4, 64);
        pA += __shfl_xor(pA, 8, 64); pB += __shfl_xor(pB, 8, 64);
        float aA = __expf(pA * 0.125f), aB = __expf(pB * 0.125f);
        den += aA + aB;
        ax += aA * (vA0 + eA0) + aB * (vB0 + eB0);
        ay += aA * (vA1 + eA1) + aB * (vB1 + eB1);
        az += aA * (vA2 + eA2) + aB * (vB2 + eB2);
        aw += aA * (vA3 + eA3) + aB * (vB3 + eB3);
    }
    if (idx < end) {
        int s = sorted[idx].x;
        uint4 kv4 = ((const uint4*)(kvt + (size_t)s * 64))[c];
        ushort4 e4 = ((const ushort4*)(ep1 + (size_t)(idx - pbeg) * 64))[c];
        float e0 = bf2f(e4.x), e1 = bf2f(e4.y), e2 = bf2f(e4.z), e3 = bf2f(e4.w);
        float k0 = bf2f((ushort)kv4.x), v0 = bf2f((ushort)(kv4.x >> 16));
        float k1 = bf2f((ushort)kv4.y), v1 = bf2f((ushort)(kv4.y >> 16));
        float k2 = bf2f((ushort)kv4.z), v2 = bf2f((ushort)(kv4.z >> 16));
        float k3 = bf2f((ushort)kv4.w), v3 = bf2f((ushort)(kv4.w >> 16));
        float p = q4.x * (k0 + e0) + q4.y * (k1 + e1) + q4.z * (k2 + e2) + q4.w * (k3 + e3);
        p += __shfl_xor(p, 1, 64);
        p += __shfl_xor(p, 2, 64);
        p += __shfl_xor(p, 4, 64);
        p += __shfl_xor(p, 8, 64);
        float a = __expf(p * 0.125f);
        den += a;
        ax += a * (v0 + e0); ay += a * (v1 + e1);
        az += a * (v2 + e2); aw += a * (v3 + e3);
    }
    den += __shfl_xor(den, 16, 64); den += __shfl_xor(den, 32, 64);
    ax += __shfl_xor(ax, 16, 64);   ax += __shfl_xor(ax, 32, 64);
    ay += __shfl_xor(ay, 16, 64);   ay += __shfl_xor(ay, 32, 64);
    az += __shfl_xor(az, 16, 64);   az += __shfl_xor(az, 32, 64);
    aw += __shfl_xor(aw, 16, 64);   aw += __shfl_xor(aw, 32, 64);
    if (g == 0) {
        float4* hp = (float4*)(h + (size_t)n * 64) + c;
        float4 hv = *hp;
        float d = den + 1e-16f;
        float4 o;
        o.x = ax / d + hv.x; o.x = o.x > 0.f ? o.x : 0.f;
        o.y = ay / d + hv.y; o.y = o.y > 0.f ? o.y : 0.f;
        o.z = az / d + hv.z; o.z = o.z > 0.f ? o.z : 0.f;
        o.w = aw / d + hv.w; o.w = o.w > 0.f ? o.w : 0.f;
        *hp = o;
    }
}

// ---------------- layer 2: one THREAD per dst node, in-lane reduction ----------
// lane owns q[16]+acc[16]; per edge: 4x uint4 kv + 2x uint4 e; zero shfl.
__global__ __launch_bounds__(256) void agg_l2(const int2* __restrict__ sorted,
        const int* __restrict__ rowptr, const ushort* __restrict__ ep2,
        const float* __restrict__ q, const uint* __restrict__ kvt,
        const float* __restrict__ skip, const int* __restrict__ batch,
        float* __restrict__ sums, float* __restrict__ cnt) {
    int n = blockIdx.x * 256 + threadIdx.x;
    if (n >= N_NODES) return;
    float qr[16];
    {
        const float4* qp = (const float4*)(q + (size_t)n * 16);
#pragma unroll
        for (int i = 0; i < 4; ++i) {
            float4 v = qp[i];
            qr[4*i] = v.x; qr[4*i+1] = v.y; qr[4*i+2] = v.z; qr[4*i+3] = v.w;
        }
    }
    float acc[16];
#pragma unroll
    for (int i = 0; i < 16; ++i) acc[i] = 0.f;
    float den = 0.f;
    int beg = rowptr[n], end = rowptr[n + 1];
    int idx = beg;
    // ---- 2-edge unrolled main loop (independent chains) ----
    for (; idx + 2 <= end; idx += 2) {
        int sA = sorted[idx].x, sB = sorted[idx + 1].x;
        const uint4* kpA = (const uint4*)(kvt + (size_t)sA * 16);
        const uint4* kpB = (const uint4*)(kvt + (size_t)sB * 16);
        uint4 kA0 = kpA[0], kA1 = kpA[1], kA2 = kpA[2], kA3 = kpA[3];
        uint4 kB0 = kpB[0], kB1 = kpB[1], kB2 = kpB[2], kB3 = kpB[3];
        const uint4* eppA = (const uint4*)(ep2 + (size_t)idx * 16);
        uint4 eA0 = eppA[0], eA1 = eppA[1];
        const uint4* eppB = (const uint4*)(ep2 + (size_t)(idx + 1) * 16);
        uint4 eB0 = eppB[0], eB1 = eppB[1];
        uint kwA[16], kwB[16], ewA[8], ewB[8];
        kwA[0]=kA0.x; kwA[1]=kA0.y; kwA[2]=kA0.z; kwA[3]=kA0.w;
        kwA[4]=kA1.x; kwA[5]=kA1.y; kwA[6]=kA1.z; kwA[7]=kA1.w;
        kwA[8]=kA2.x; kwA[9]=kA2.y; kwA[10]=kA2.z; kwA[11]=kA2.w;
        kwA[12]=kA3.x; kwA[13]=kA3.y; kwA[14]=kA3.z; kwA[15]=kA3.w;
        kwB[0]=kB0.x; kwB[1]=kB0.y; kwB[2]=kB0.z; kwB[3]=kB0.w;
        kwB[4]=kB1.x; kwB[5]=kB1.y; kwB[6]=kB1.z; kwB[7]=kB1.w;
        kwB[8]=kB2.x; kwB[9]=kB2.y; kwB[10]=kB2.z; kwB[11]=kB2.w;
        kwB[12]=kB3.x; kwB[13]=kB3.y; kwB[14]=kB3.z; kwB[15]=kB3.w;
        ewA[0]=eA0.x; ewA[1]=eA0.y; ewA[2]=eA0.z; ewA[3]=eA0.w;
        ewA[4]=eA1.x; ewA[5]=eA1.y; ewA[6]=eA1.z; ewA[7]=eA1.w;
        ewB[0]=eB0.x; ewB[1]=eB0.y; ewB[2]=eB0.z; ewB[3]=eB0.w;
        ewB[4]=eB1.x; ewB[5]=eB1.y; ewB[6]=eB1.z; ewB[7]=eB1.w;
        float pA = 0.f, pB = 0.f;
#pragma unroll
        for (int c = 0; c < 16; ++c) {
            float eAc = bf2f((ushort)(ewA[c >> 1] >> ((c & 1) * 16)));
            float eBc = bf2f((ushort)(ewB[c >> 1] >> ((c & 1) * 16)));
            pA += qr[c] * (bf2f((ushort)kwA[c]) + eAc);
            pB += qr[c] * (bf2f((ushort)kwB[c]) + eBc);
        }
        float aA = __expf(pA * 0.25f), aB = __expf(pB * 0.25f);
        den += aA + aB;
#pragma unroll
        for (int c = 0; c < 16; ++c) {
            float eAc = bf2f((ushort)(ewA[c >> 1] >> ((c & 1) * 16)));
            float eBc = bf2f((ushort)(ewB[c >> 1] >> ((c & 1) * 16)));
            acc[c] += aA * (bf2f((ushort)(kwA[c] >> 16)) + eAc)
                    + aB * (bf2f((ushort)(kwB[c] >> 16)) + eBc);
        }
    }
    // ---- tail (0 or 1 edge) ----
    if (idx < end) {
        int sA = sorted[idx].x;
        const uint4* kpA = (const uint4*)(kvt + (size_t)sA * 16);
        uint4 kA0 = kpA[0], kA1 = kpA[1], kA2 = kpA[2], kA3 = kpA[3];
        const uint4* eppA = (const uint4*)(ep2 + (size_t)idx * 16);
        uint4 eA0 = eppA[0], eA1 = eppA[1];
        uint kwA[16], ewA[8];
        kwA[0]=kA0.x; kwA[1]=kA0.y; kwA[2]=kA0.z; kwA[3]=kA0.w;
        kwA[4]=kA1.x; kwA[5]=kA1.y; kwA[6]=kA1.z; kwA[7]=kA1.w;
        kwA[8]=kA2.x; kwA[9]=kA2.y; kwA[10]=kA2.z; kwA[11]=kA2.w;
        kwA[12]=kA3.x; kwA[13]=kA3.y; kwA[14]=kA3.z; kwA[15]=kA3.w;
        ewA[0]=eA0.x; ewA[1]=eA0.y; ewA[2]=eA0.z; ewA[3]=eA0.w;
        ewA[4]=eA1.x; ewA[5]=eA1.y; ewA[6]=eA1.z; ewA[7]=eA1.w;
        float pA = 0.f;
#pragma unroll
        for (int c = 0; c < 16; ++c) {
            float eAc = bf2f((ushort)(ewA[c >> 1] >> ((c & 1) * 16)));
            pA += qr[c] * (bf2f((ushort)kwA[c]) + eAc);
        }
        float aA = __expf(pA * 0.25f);
        den += aA;
#pragma unroll
        for (int c = 0; c < 16; ++c) {
            float eAc = bf2f((ushort)(ewA[c >> 1] >> ((c & 1) * 16)));
            acc[c] += aA * (bf2f((ushort)(kwA[c] >> 16)) + eAc);
        }
    }
    // ---- epilogue: h2 = relu(acc/den + skip); pool ----
    float d = den + 1e-16f;
    const float4* sp = (const float4*)(skip + (size_t)n * 16);
    int gb = batch[n];
#pragma unroll
    for (int i = 0; i < 4; ++i) {
        float4 sv = sp[i];
        float r0 = acc[4*i]     / d + sv.x; r0 = r0 > 0.f ? r0 : 0.f;
        float r1 = acc[4*i + 1] / d + sv.y; r1 = r1 > 0.f ? r1 : 0.f;
        float r2 = acc[4*i + 2] / d + sv.z; r2 = r2 > 0.f ? r2 : 0.f;
        float r3 = acc[4*i + 3] / d + sv.w; r3 = r3 > 0.f ? r3 : 0.f;
        atomicAdd(sums + gb * 16 + 4*i,     r0);
        atomicAdd(sums + gb * 16 + 4*i + 1, r1);
        atomicAdd(sums + gb * 16 + 4*i + 2, r2);
        atomicAdd(sums + gb * 16 + 4*i + 3, r3);
    }
    atomicAdd(cnt + gb, 1.0f);
}

// ---------------- final fc + sigmoid ----------------
__global__ void final_fc(const float* __restrict__ sums, const float* __restrict__ cnt,
                         const float* __restrict__ Wf, const float* __restrict__ bf,
                         float* __restrict__ out) {
    int g = blockIdx.x * blockDim.x + threadIdx.x;
    if (g >= N_GRAPHS) return;
    float cc = cnt[g];
    cc = cc > 1.f ? cc : 1.f;
    float acc = bf[0];
#pragma unroll
    for (int c = 0; c < 16; ++c) acc += (sums[g * 16 + c] / cc) * Wf[c];
    out[g] = 1.f / (1.f + expf(-acc));
}

extern "C" void kernel_launch(void* const* d_in, const int* in_sizes, int n_in,
                              void* d_out, int out_size, void* d_ws, size_t ws_size,
                              hipStream_t stream) {
    const float* x    = (const float*)d_in[0];
    const float* ea   = (const float*)d_in[1];
    const float* Wq1  = (const float*)d_in[2];
    const float* bq1  = (const float*)d_in[3];
    const float* Wk1  = (const float*)d_in[4];
    const float* bk1  = (const float*)d_in[5];
    const float* Wv1  = (const float*)d_in[6];
    const float* bv1  = (const float*)d_in[7];
    const float* We1  = (const float*)d_in[8];
    const float* Ws1  = (const float*)d_in[9];
    const float* bs1  = (const float*)d_in[10];
    const float* Wq2  = (const float*)d_in[11];
    const float* bq2  = (const float*)d_in[12];
    const float* Wk2  = (const float*)d_in[13];
    const float* bk2  = (const float*)d_in[14];
    const float* Wv2  = (const float*)d_in[15];
    const float* bv2  = (const float*)d_in[16];
    const float* We2  = (const float*)d_in[17];
    const float* Ws2  = (const float*)d_in[18];
    const float* bs2  = (const float*)d_in[19];
    const float* Wf   = (const float*)d_in[20];
    const float* bf   = (const float*)d_in[21];
    const int*   ei   = (const int*)d_in[22];
    const int*   batch= (const int*)d_in[23];
    float* out = (float*)d_out;

    // -------- workspace layout (~216 MB + 64 KB) --------
    float* ws = (float*)d_ws;
    size_t off = 0;
    float* q1    = ws + off;          off += (size_t)N_NODES * 64;
    uint* kvt1   = (uint*)(ws + off); off += (size_t)N_NODES * 64;
    float* s1    = ws + off;          off += (size_t)N_NODES * 64;   // skip -> h1
    float* q2    = ws + off;          off += (size_t)N_NODES * 16;
    uint* kvt2   = (uint*)(ws + off); off += (size_t)N_NODES * 16;
    float* s2    = ws + off;          off += (size_t)N_NODES * 16;
    int2* sorted = (int2*)(ws + off); off += (size_t)N_EDGES * 2;
    ushort* ep1  = (ushort*)(ws + off); off += (size_t)CHUNK_EDGE_CAP * 32;  // chunk-local
    ushort* ep2  = (ushort*)(ws + off); off += (size_t)N_EDGES * 8;          // global
    int* rowptr  = (int*)(ws + off);  off += N_NODES + 2;
    int* cursor  = (int*)(ws + off);  off += N_NODES;
    int* bsum    = (int*)(ws + off);  off += 512;
    // ---- contiguous zero block ----
    float* zerop = ws + off;
    int*   deg   = (int*)(ws + off);  off += N_NODES;
    float* sums  = ws + off;          off += (size_t)N_GRAPHS * 16;
    float* cnt   = ws + off;          off += N_GRAPHS;
    size_t zero_bytes = ((size_t)N_NODES + N_GRAPHS * 16 + N_GRAPHS) * sizeof(float);
    off = (off + 3) & ~(size_t)3;
    __half* Bpack = (__half*)(ws + off); off += 16384;   // 64 KB
    // alias: xh (fp16 x) on ep1 (dead before edge_mlp1)
    __half* xh = (__half*)ep1;

    hipMemsetAsync(zerop, 0, zero_bytes, stream);

    // -------- prep: x->fp16, W->fp16 fragment pack --------
    conv_x<<<6250, 256, 0, stream>>>(x, xh);
    prepack_W<<<16, 256, 0, stream>>>(Wq1, Wk1, Wv1, Ws1, Bpack);

    // -------- CSR build (shared by both layers) --------
    hist_kernel<<<(N_EDGES + 255) / 256, 256, 0, stream>>>(ei, deg);
    scan_block<<<NB_SCAN, 256, 0, stream>>>(deg, rowptr, bsum);
    scan_bsum<<<1, 512, 0, stream>>>(bsum);
    scan_add<<<NB_SCAN, 256, 0, stream>>>(rowptr, cursor, bsum);
    scatter_kernel<<<(N_EDGES + 255) / 256, 256, 0, stream>>>(ei, cursor, sorted);

    // -------- layer 1 node linear (MFMA) --------
    node_lin1_mfma<<<(N_NODES + 63) / 64, 256, 0, stream>>>(xh, bq1, bk1, bv1, bs1,
                                                            Bpack, q1, kvt1, s1);

    // -------- layer 1 (chunked: staged fused edge MLP -> aggregation) --------
    int mlp_blocks = (CHUNK_EDGE_CAP + 63) / 64;
    for (int c = 0; c < 4; ++c) {
        int n0 = c * NODES_PER_CHUNK;
        int n1 = (c + 1) * NODES_PER_CHUNK;
        if (n1 > N_NODES) n1 = N_NODES;
        edge_mlp1<<<mlp_blocks, 256, 0, stream>>>(sorted, rowptr, n0, n1, ea,
                                                  We1, We2, ep1, ep2);
        agg_l1<<<(NODES_PER_CHUNK + 3) / 4, 256, 0, stream>>>(sorted, rowptr, ep1,
                                                              q1, kvt1, s1, n0, n1);
    }

    // -------- layer 2 --------
    node_lin2<<<(N_NODES + 31) / 32, 256, 0, stream>>>(s1, Wq2, bq2, Wk2, bk2, Wv2, bv2,
                                                       Ws2, bs2, q2, kvt2, s2);
    agg_l2<<<(N_NODES + 255) / 256, 256, 0, stream>>>(sorted, rowptr, ep2, q2, kvt2,
                                                      s2, batch, sums, cnt);

    // -------- final fc --------
    final_fc<<<(N_GRAPHS + 255) / 256, 256, 0, stream>>>(sums, cnt, Wf, bf, out);
}

// Round 16
// 777.834 us; speedup vs baseline: 1.2167x; 1.1067x over previous
//
#include <hip/hip_runtime.h>
#include <hip/hip_bf16.h>
#include <hip/hip_fp16.h>
#include <math.h>

#define N_NODES 100000
#define N_EDGES 1600000
#define N_GRAPHS 1024
#define NB_SCAN ((N_NODES + 255) / 256)   // 391
#define NODES_PER_CHUNK 25000             // layer-1 chunks (4)
#define CHUNK_EDGE_CAP 450000             // +90 sigma margin

typedef _Float16 f16x8 __attribute__((ext_vector_type(8)));
typedef float f32x4 __attribute__((ext_vector_type(4)));

static __device__ __forceinline__ float bf2f(ushort u) {
    return __uint_as_float(((unsigned)u) << 16);
}
static __device__ __forceinline__ ushort f2bf(float f) {
    unsigned x = __float_as_uint(f);
    return (ushort)((x + 0x7fffu + ((x >> 16) & 1u)) >> 16);   // RNE
}

// ---------------- x -> fp16 (streaming) ----------------
__global__ __launch_bounds__(256) void conv_x(const float* __restrict__ x,
                                              __half* __restrict__ xh) {
    int i = blockIdx.x * blockDim.x + threadIdx.x;
    const float4* src = (const float4*)x;
    float4 a = src[2 * i], b = src[2 * i + 1];
    __half2 h0 = __floats2half2_rn(a.x, a.y);
    __half2 h1 = __floats2half2_rn(a.z, a.w);
    __half2 h2 = __floats2half2_rn(b.x, b.y);
    __half2 h3 = __floats2half2_rn(b.z, b.w);
    uint4 o = make_uint4(*(uint*)&h0, *(uint*)&h1, *(uint*)&h2, *(uint*)&h3);
    ((uint4*)xh)[i] = o;
}

// ---------------- W -> fp16 in B-fragment order ----------------
__global__ __launch_bounds__(256) void prepack_W(const float* __restrict__ Wq,
        const float* __restrict__ Wk, const float* __restrict__ Wv,
        const float* __restrict__ Ws, __half* __restrict__ Bpack) {
    int tid = blockIdx.x * 256 + threadIdx.x;
    if (tid >= 4 * 4 * 4 * 64) return;
    int lane = tid & 63, nt = (tid >> 6) & 3, kt = (tid >> 8) & 3, w = (tid >> 10) & 3;
    const float* W = (w == 0) ? Wq : (w == 1) ? Wk : (w == 2) ? Wv : Ws;
    int col = nt * 16 + (lane & 15);
    int kbase = kt * 32 + (lane >> 4) * 8;
    __half* dst = Bpack + (size_t)tid * 8;
#pragma unroll
    for (int j = 0; j < 8; ++j) dst[j] = __float2half(W[(kbase + j) * 64 + col]);
}

// ---------------- layer 1 node linear via MFMA ----------------
__global__ __launch_bounds__(256) void node_lin1_mfma(const __half* __restrict__ xh,
        const float* __restrict__ bq, const float* __restrict__ bk,
        const float* __restrict__ bv, const float* __restrict__ bs,
        const __half* __restrict__ Bpack,
        float* __restrict__ q, uint* __restrict__ kvt, float* __restrict__ s) {
    __shared__ _Float16 As[64][136];
    int tid = threadIdx.x;
    int nb = blockIdx.x * 64;
    {
        int row = tid >> 2, seg = tid & 3;
        int nn = nb + row;
        uint4* dst = (uint4*)&As[row][seg * 32];
        if (nn < N_NODES) {
            const uint4* sp = (const uint4*)(xh + (size_t)nn * 128 + seg * 32);
            dst[0] = sp[0]; dst[1] = sp[1]; dst[2] = sp[2]; dst[3] = sp[3];
        } else {
            uint4 z = make_uint4(0, 0, 0, 0);
            dst[0] = z; dst[1] = z; dst[2] = z; dst[3] = z;
        }
    }
    __syncthreads();
    int wv = tid >> 6, lane = tid & 63;
    const f16x8* Bp = (const f16x8*)Bpack;
    f16x8 Bf[4][4];
#pragma unroll
    for (int kt = 0; kt < 4; ++kt)
#pragma unroll
        for (int nt = 0; nt < 4; ++nt)
            Bf[kt][nt] = Bp[((wv * 4 + kt) * 4 + nt) * 64 + lane];
    f32x4 acc[4][4];
#pragma unroll
    for (int mt = 0; mt < 4; ++mt)
#pragma unroll
        for (int nt = 0; nt < 4; ++nt) acc[mt][nt] = (f32x4){0.f, 0.f, 0.f, 0.f};
    int arow = lane & 15, akoff = (lane >> 4) * 8;
#pragma unroll
    for (int kt = 0; kt < 4; ++kt) {
        f16x8 a[4];
#pragma unroll
        for (int mt = 0; mt < 4; ++mt)
            a[mt] = *(const f16x8*)&As[mt * 16 + arow][kt * 32 + akoff];
#pragma unroll
        for (int mt = 0; mt < 4; ++mt)
#pragma unroll
            for (int nt = 0; nt < 4; ++nt)
                acc[mt][nt] = __builtin_amdgcn_mfma_f32_16x16x32_f16(
                    a[mt], Bf[kt][nt], acc[mt][nt], 0, 0, 0);
    }
    const float* bvec = (wv == 0) ? bq : (wv == 1) ? bk : (wv == 2) ? bv : bs;
    int colw = lane & 15;
    int rgrp = (lane >> 4) * 4;
#pragma unroll
    for (int nt = 0; nt < 4; ++nt) {
        float bias = bvec[nt * 16 + colw];
        int col = nt * 16 + colw;
#pragma unroll
        for (int mt = 0; mt < 4; ++mt) {
#pragma unroll
            for (int r = 0; r < 4; ++r) {
                int node = nb + mt * 16 + rgrp + r;
                if (node >= N_NODES) continue;
                float val = acc[mt][nt][r] + bias;
                if (wv == 0)      q[(size_t)node * 64 + col] = val;
                else if (wv == 1) ((ushort*)kvt)[((size_t)node * 64 + col) * 2]     = f2bf(val);
                else if (wv == 2) ((ushort*)kvt)[((size_t)node * 64 + col) * 2 + 1] = f2bf(val);
                else              s[(size_t)node * 64 + col] = val;
            }
        }
    }
}

// ---------------- layer 2: node linear (64 -> 16) x4 ----------------
__global__ __launch_bounds__(256) void node_lin2(const float* __restrict__ h,
                          const float* __restrict__ Wq, const float* __restrict__ bq,
                          const float* __restrict__ Wk, const float* __restrict__ bk,
                          const float* __restrict__ Wv, const float* __restrict__ bv,
                          const float* __restrict__ Ws, const float* __restrict__ bs,
                          float* __restrict__ q, uint* __restrict__ kvt,
                          float* __restrict__ s) {
    __shared__ float hs[32][65];
    int tid = threadIdx.x;
    int nb = blockIdx.x * 32;
    for (int i = tid; i < 32 * 64; i += 256) {
        int nn = nb + (i >> 6);
        hs[i >> 6][i & 63] = (nn < N_NODES) ? h[(size_t)nb * 64 + i] : 0.f;
    }
    __syncthreads();
    int w = tid >> 6, t = tid & 63, g = t >> 4, c = t & 15;
    const float* W = (w == 0) ? Wq : (w == 1) ? Wk : (w == 2) ? Wv : Ws;
    const float* b = (w == 0) ? bq : (w == 1) ? bk : (w == 2) ? bv : bs;
    float acc[8];
#pragma unroll
    for (int n = 0; n < 8; ++n) acc[n] = 0.f;
#pragma unroll 4
    for (int j = 0; j < 64; ++j) {
        float wv = W[j * 16 + c];
#pragma unroll
        for (int n = 0; n < 8; ++n) acc[n] += hs[g * 8 + n][j] * wv;
    }
    float bb = b[c];
#pragma unroll
    for (int n = 0; n < 8; ++n) {
        int nn = nb + g * 8 + n;
        if (nn >= N_NODES) break;
        float r = acc[n] + bb;
        if (w == 0)      q[(size_t)nn * 16 + c] = r;
        else if (w == 1) ((ushort*)kvt)[((size_t)nn * 16 + c) * 2]     = f2bf(r);
        else if (w == 2) ((ushort*)kvt)[((size_t)nn * 16 + c) * 2 + 1] = f2bf(r);
        else             s[(size_t)nn * 16 + c] = r;
    }
}

// ---------------- CSR build: histogram -> scan -> scatter ----------------
__global__ void hist_kernel(const int* __restrict__ ei, int* __restrict__ deg) {
    int e = blockIdx.x * blockDim.x + threadIdx.x;
    if (e < N_EDGES) atomicAdd(deg + ei[N_EDGES + e], 1);
}

__global__ __launch_bounds__(256) void scan_block(const int* __restrict__ deg,
        int* __restrict__ rowptr, int* __restrict__ bsum) {
    __shared__ int sd[256];
    int i = blockIdx.x * 256 + threadIdx.x;
    int v = (i < N_NODES) ? deg[i] : 0;
    sd[threadIdx.x] = v;
    __syncthreads();
    for (int off = 1; off < 256; off <<= 1) {
        int add = (threadIdx.x >= off) ? sd[threadIdx.x - off] : 0;
        __syncthreads();
        sd[threadIdx.x] += add;
        __syncthreads();
    }
    if (i < N_NODES) rowptr[i] = sd[threadIdx.x] - v;   // exclusive within block
    if (threadIdx.x == 255) bsum[blockIdx.x] = sd[255];
}

__global__ __launch_bounds__(512) void scan_bsum(int* __restrict__ bsum) {
    __shared__ int sd[512];
    int t = threadIdx.x;
    int v = (t < NB_SCAN) ? bsum[t] : 0;
    sd[t] = v;
    __syncthreads();
    for (int off = 1; off < 512; off <<= 1) {
        int add = (t >= off) ? sd[t - off] : 0;
        __syncthreads();
        sd[t] += add;
        __syncthreads();
    }
    if (t < NB_SCAN) bsum[t] = sd[t] - v;               // exclusive
}

__global__ void scan_add(int* __restrict__ rowptr, int* __restrict__ cursor,
                         const int* __restrict__ bsum) {
    int i = blockIdx.x * blockDim.x + threadIdx.x;
    if (i < N_NODES) {
        int r = rowptr[i] + bsum[i >> 8];
        rowptr[i] = r;
        cursor[i] = r;
    }
    if (i == 0) rowptr[N_NODES] = N_EDGES;
}

__global__ void scatter_kernel(const int* __restrict__ ei, int* __restrict__ cursor,
                               int2* __restrict__ sorted) {
    int e = blockIdx.x * blockDim.x + threadIdx.x;
    if (e >= N_EDGES) return;
    int d = ei[N_EDGES + e];
    int pos = atomicAdd(cursor + d, 1);
    sorted[pos] = make_int2(ei[e], e);   // (src, eid)
}

// ------- fused edge MLP: e1 (64ch, chunk-local) + e2 (16ch, global), staged -------
__global__ __launch_bounds__(256) void edge_mlp1(const int2* __restrict__ sorted,
        const int* __restrict__ rowptr, int n0, int n1,
        const float* __restrict__ ea, const float* __restrict__ We1,
        const float* __restrict__ We2,
        ushort* __restrict__ ep1, ushort* __restrict__ ep2) {
    __shared__ float ea_s[64][36];
    int pbeg = rowptr[n0], pend = rowptr[n1];
    int base = pbeg + blockIdx.x * 64;
    if (base >= pend) return;
    int nedges = pend - base; if (nedges > 64) nedges = 64;
    int tid = threadIdx.x;
    int e4 = tid >> 2, r = tid & 3;
    if (e4 < nedges) {
        int eid = sorted[base + e4].y;
        const float4* src = (const float4*)(ea + (size_t)eid * 32);
        ((float4*)ea_s[e4])[r * 2]     = src[r * 2];
        ((float4*)ea_s[e4])[r * 2 + 1] = src[r * 2 + 1];
    }
    __syncthreads();
    int w = tid >> 6, t = tid & 63;
    int c2 = t & 15, j0 = (t >> 4) * 8;
    float we[32];
#pragma unroll
    for (int j = 0; j < 32; ++j) we[j] = We1[j * 64 + t];
    float we2p[8];
#pragma unroll
    for (int i = 0; i < 8; ++i) we2p[i] = We2[(j0 + i) * 16 + c2];
    int e0 = w * 16;
    int ecnt = nedges - e0; if (ecnt > 16) ecnt = 16;
    for (int e = 0; e < ecnt; ++e) {
        const float4* row = (const float4*)ea_s[e0 + e];
        float et = 0.f;
#pragma unroll
        for (int r2 = 0; r2 < 8; ++r2) {
            float4 f = row[r2];
            et += f.x * we[4*r2] + f.y * we[4*r2+1] + f.z * we[4*r2+2] + f.w * we[4*r2+3];
        }
        ep1[(size_t)(base - pbeg + e0 + e) * 64 + t] = f2bf(et);
        const float* rowf = ea_s[e0 + e] + j0;
        float p2 = rowf[0] * we2p[0] + rowf[1] * we2p[1] + rowf[2] * we2p[2]
                 + rowf[3] * we2p[3] + rowf[4] * we2p[4] + rowf[5] * we2p[5]
                 + rowf[6] * we2p[6] + rowf[7] * we2p[7];
        p2 += __shfl_xor(p2, 16, 64);
        p2 += __shfl_xor(p2, 32, 64);
        if (t < 16) ep2[(size_t)(base + e0 + e) * 16 + t] = f2bf(p2);
    }
}

// ---------------- layer 1: per-dst attention, 16-lane groups, 2-edge ILP ----
__global__ __launch_bounds__(256) void agg_l1(const int2* __restrict__ sorted,
        const int* __restrict__ rowptr, const ushort* __restrict__ ep1,
        const float* __restrict__ q, const uint* __restrict__ kvt,
        float* __restrict__ h, int n0, int n1) {
    int w = threadIdx.x >> 6, t = threadIdx.x & 63;
    int n = n0 + blockIdx.x * 4 + w;
    if (n >= n1) return;
    int g = t >> 4, c = t & 15;
    int pbeg = rowptr[n0];
    float4 q4 = ((const float4*)(q + (size_t)n * 64))[c];
    int beg = rowptr[n], end = rowptr[n + 1];
    float den = 0.f;
    float ax = 0.f, ay = 0.f, az = 0.f, aw = 0.f;
    int idx = beg + g;
    for (; idx + 4 < end; idx += 8) {
        int sA = sorted[idx].x, sB = sorted[idx + 4].x;
        uint4 kvA = ((const uint4*)(kvt + (size_t)sA * 64))[c];
        uint4 kvB = ((const uint4*)(kvt + (size_t)sB * 64))[c];
        ushort4 eA = ((const ushort4*)(ep1 + (size_t)(idx - pbeg) * 64))[c];
        ushort4 eB = ((const ushort4*)(ep1 + (size_t)(idx + 4 - pbeg) * 64))[c];
        float eA0 = bf2f(eA.x), eA1 = bf2f(eA.y), eA2 = bf2f(eA.z), eA3 = bf2f(eA.w);
        float eB0 = bf2f(eB.x), eB1 = bf2f(eB.y), eB2 = bf2f(eB.z), eB3 = bf2f(eB.w);
        float kA0 = bf2f((ushort)kvA.x), vA0 = bf2f((ushort)(kvA.x >> 16));
        float kA1 = bf2f((ushort)kvA.y), vA1 = bf2f((ushort)(kvA.y >> 16));
        float kA2 = bf2f((ushort)kvA.z), vA2 = bf2f((ushort)(kvA.z >> 16));
        float kA3 = bf2f((ushort)kvA.w), vA3 = bf2f((ushort)(kvA.w >> 16));
        float kB0 = bf2f((ushort)kvB.x), vB0 = bf2f((ushort)(kvB.x >> 16));
        float kB1 = bf2f((ushort)kvB.y), vB1 = bf2f((ushort)(kvB.y >> 16));
        float kB2 = bf2f((ushort)kvB.z), vB2 = bf2f((ushort)(kvB.z >> 16));
        float kB3 = bf2f((ushort)kvB.w), vB3 = bf2f((ushort)(kvB.w >> 16));
        float pA = q4.x * (kA0 + eA0) + q4.y * (kA1 + eA1)
                 + q4.z * (kA2 + eA2) + q4.w * (kA3 + eA3);
        float pB = q4.x * (kB0 + eB0) + q4.y * (kB1 + eB1)
                 + q4.z * (kB2 + eB2) + q4.w * (kB3 + eB3);
        pA += __shfl_xor(pA, 1, 64); pB += __shfl_xor(pB, 1, 64);
        pA += __shfl_xor(pA, 2, 64); pB += __shfl_xor(pB, 2, 64);
        pA += __shfl_xor(pA, 4, 64); pB += __shfl_xor(pB, 4, 64);
        pA += __shfl_xor(pA, 8, 64); pB += __shfl_xor(pB, 8, 64);
        float aA = __expf(pA * 0.125f), aB = __expf(pB * 0.125f);
        den += aA + aB;
        ax += aA * (vA0 + eA0) + aB * (vB0 + eB0);
        ay += aA * (vA1 + eA1) + aB * (vB1 + eB1);
        az += aA * (vA2 + eA2) + aB * (vB2 + eB2);
        aw += aA * (vA3 + eA3) + aB * (vB3 + eB3);
    }
    if (idx < end) {
        int s = sorted[idx].x;
        uint4 kv4 = ((const uint4*)(kvt + (size_t)s * 64))[c];
        ushort4 e4 = ((const ushort4*)(ep1 + (size_t)(idx - pbeg) * 64))[c];
        float e0 = bf2f(e4.x), e1 = bf2f(e4.y), e2 = bf2f(e4.z), e3 = bf2f(e4.w);
        float k0 = bf2f((ushort)kv4.x), v0 = bf2f((ushort)(kv4.x >> 16));
        float k1 = bf2f((ushort)kv4.y), v1 = bf2f((ushort)(kv4.y >> 16));
        float k2 = bf2f((ushort)kv4.z), v2 = bf2f((ushort)(kv4.z >> 16));
        float k3 = bf2f((ushort)kv4.w), v3 = bf2f((ushort)(kv4.w >> 16));
        float p = q4.x * (k0 + e0) + q4.y * (k1 + e1) + q4.z * (k2 + e2) + q4.w * (k3 + e3);
        p += __shfl_xor(p, 1, 64);
        p += __shfl_xor(p, 2, 64);
        p += __shfl_xor(p, 4, 64);
        p += __shfl_xor(p, 8, 64);
        float a = __expf(p * 0.125f);
        den += a;
        ax += a * (v0 + e0); ay += a * (v1 + e1);
        az += a * (v2 + e2); aw += a * (v3 + e3);
    }
    den += __shfl_xor(den, 16, 64); den += __shfl_xor(den, 32, 64);
    ax += __shfl_xor(ax, 16, 64);   ax += __shfl_xor(ax, 32, 64);
    ay += __shfl_xor(ay, 16, 64);   ay += __shfl_xor(ay, 32, 64);
    az += __shfl_xor(az, 16, 64);   az += __shfl_xor(az, 32, 64);
    aw += __shfl_xor(aw, 16, 64);   aw += __shfl_xor(aw, 32, 64);
    if (g == 0) {
        float4* hp = (float4*)(h + (size_t)n * 64) + c;
        float4 hv = *hp;
        float d = den + 1e-16f;
        float4 o;
        o.x = ax / d + hv.x; o.x = o.x > 0.f ? o.x : 0.f;
        o.y = ay / d + hv.y; o.y = o.y > 0.f ? o.y : 0.f;
        o.z = az / d + hv.z; o.z = o.z > 0.f ? o.z : 0.f;
        o.w = aw / d + hv.w; o.w = o.w > 0.f ? o.w : 0.f;
        *hp = o;
    }
}

// ---------------- layer 2: per-dst attention + mean-pool, 4-edge ILP ----------
__global__ __launch_bounds__(256) void agg_l2(const int2* __restrict__ sorted,
        const int* __restrict__ rowptr, const ushort* __restrict__ ep2,
        const float* __restrict__ q, const uint* __restrict__ kvt,
        const float* __restrict__ skip, const int* __restrict__ batch,
        float* __restrict__ sums, float* __restrict__ cnt) {
    int w = threadIdx.x >> 6, t = threadIdx.x & 63;
    int n = blockIdx.x * 4 + w;
    if (n >= N_NODES) return;
    int g = t >> 4, c = t & 15;
    float qv = q[(size_t)n * 16 + c];
    int beg = rowptr[n], end = rowptr[n + 1];
    float den = 0.f, acc = 0.f;
    int idx = beg + g;
    for (; idx + 12 < end; idx += 16) {
        int sA = sorted[idx].x,      sB = sorted[idx + 4].x;
        int sC = sorted[idx + 8].x,  sD = sorted[idx + 12].x;
        uint kvA = kvt[(size_t)sA * 16 + c];
        uint kvB = kvt[(size_t)sB * 16 + c];
        uint kvC = kvt[(size_t)sC * 16 + c];
        uint kvD = kvt[(size_t)sD * 16 + c];
        float eA = bf2f(ep2[(size_t)idx * 16 + c]);
        float eB = bf2f(ep2[(size_t)(idx + 4) * 16 + c]);
        float eC = bf2f(ep2[(size_t)(idx + 8) * 16 + c]);
        float eD = bf2f(ep2[(size_t)(idx + 12) * 16 + c]);
        float pA = qv * (bf2f((ushort)kvA) + eA);
        float pB = qv * (bf2f((ushort)kvB) + eB);
        float pC = qv * (bf2f((ushort)kvC) + eC);
        float pD = qv * (bf2f((ushort)kvD) + eD);
        pA += __shfl_xor(pA, 8, 64); pB += __shfl_xor(pB, 8, 64);
        pC += __shfl_xor(pC, 8, 64); pD += __shfl_xor(pD, 8, 64);
        pA += __shfl_xor(pA, 4, 64); pB += __shfl_xor(pB, 4, 64);
        pC += __shfl_xor(pC, 4, 64); pD += __shfl_xor(pD, 4, 64);
        pA += __shfl_xor(pA, 2, 64); pB += __shfl_xor(pB, 2, 64);
        pC += __shfl_xor(pC, 2, 64); pD += __shfl_xor(pD, 2, 64);
        pA += __shfl_xor(pA, 1, 64); pB += __shfl_xor(pB, 1, 64);
        pC += __shfl_xor(pC, 1, 64); pD += __shfl_xor(pD, 1, 64);
        float aA = __expf(pA * 0.25f), aB = __expf(pB * 0.25f);
        float aC = __expf(pC * 0.25f), aD = __expf(pD * 0.25f);
        den += (aA + aB) + (aC + aD);
        acc += aA * (bf2f((ushort)(kvA >> 16)) + eA)
             + aB * (bf2f((ushort)(kvB >> 16)) + eB)
             + aC * (bf2f((ushort)(kvC >> 16)) + eC)
             + aD * (bf2f((ushort)(kvD >> 16)) + eD);
    }
    for (; idx + 4 < end; idx += 8) {
        int sA = sorted[idx].x, sB = sorted[idx + 4].x;
        uint kvA = kvt[(size_t)sA * 16 + c];
        uint kvB = kvt[(size_t)sB * 16 + c];
        float eA = bf2f(ep2[(size_t)idx * 16 + c]);
        float eB = bf2f(ep2[(size_t)(idx + 4) * 16 + c]);
        float pA = qv * (bf2f((ushort)kvA) + eA);
        float pB = qv * (bf2f((ushort)kvB) + eB);
        pA += __shfl_xor(pA, 8, 64); pB += __shfl_xor(pB, 8, 64);
        pA += __shfl_xor(pA, 4, 64); pB += __shfl_xor(pB, 4, 64);
        pA += __shfl_xor(pA, 2, 64); pB += __shfl_xor(pB, 2, 64);
        pA += __shfl_xor(pA, 1, 64); pB += __shfl_xor(pB, 1, 64);
        float aA = __expf(pA * 0.25f), aB = __expf(pB * 0.25f);
        den += aA + aB;
        acc += aA * (bf2f((ushort)(kvA >> 16)) + eA)
             + aB * (bf2f((ushort)(kvB >> 16)) + eB);
    }
    if (idx < end) {
        int s = sorted[idx].x;
        uint kvp = kvt[(size_t)s * 16 + c];
        float e2 = bf2f(ep2[(size_t)idx * 16 + c]);
        float p = qv * (bf2f((ushort)kvp) + e2);
        p += __shfl_xor(p, 8, 64);
        p += __shfl_xor(p, 4, 64);
        p += __shfl_xor(p, 2, 64);
        p += __shfl_xor(p, 1, 64);
        float a = __expf(p * 0.25f);
        den += a;
        acc += a * (bf2f((ushort)(kvp >> 16)) + e2);
    }
    den += __shfl_xor(den, 16, 64);
    den += __shfl_xor(den, 32, 64);
    acc += __shfl_xor(acc, 16, 64);
    acc += __shfl_xor(acc, 32, 64);
    if (t < 16) {
        float r2 = acc / (den + 1e-16f) + skip[(size_t)n * 16 + c];
        r2 = r2 > 0.f ? r2 : 0.f;
        int gb = batch[n];
        atomicAdd(sums + gb * 16 + c, r2);
        if (c == 0) atomicAdd(cnt + gb, 1.0f);
    }
}

// ---------------- final fc + sigmoid ----------------
__global__ void final_fc(const float* __restrict__ sums, const float* __restrict__ cnt,
                         const float* __restrict__ Wf, const float* __restrict__ bf,
                         float* __restrict__ out) {
    int g = blockIdx.x * blockDim.x + threadIdx.x;
    if (g >= N_GRAPHS) return;
    float cc = cnt[g];
    cc = cc > 1.f ? cc : 1.f;
    float acc = bf[0];
#pragma unroll
    for (int c = 0; c < 16; ++c) acc += (sums[g * 16 + c] / cc) * Wf[c];
    out[g] = 1.f / (1.f + expf(-acc));
}

extern "C" void kernel_launch(void* const* d_in, const int* in_sizes, int n_in,
                              void* d_out, int out_size, void* d_ws, size_t ws_size,
                              hipStream_t stream) {
    const float* x    = (const float*)d_in[0];
    const float* ea   = (const float*)d_in[1];
    const float* Wq1  = (const float*)d_in[2];
    const float* bq1  = (const float*)d_in[3];
    const float* Wk1  = (const float*)d_in[4];
    const float* bk1  = (const float*)d_in[5];
    const float* Wv1  = (const float*)d_in[6];
    const float* bv1  = (const float*)d_in[7];
    const float* We1  = (const float*)d_in[8];
    const float* Ws1  = (const float*)d_in[9];
    const float* bs1  = (const float*)d_in[10];
    const float* Wq2  = (const float*)d_in[11];
    const float* bq2  = (const float*)d_in[12];
    const float* Wk2  = (const float*)d_in[13];
    const float* bk2  = (const float*)d_in[14];
    const float* Wv2  = (const float*)d_in[15];
    const float* bv2  = (const float*)d_in[16];
    const float* We2  = (const float*)d_in[17];
    const float* Ws2  = (const float*)d_in[18];
    const float* bs2  = (const float*)d_in[19];
    const float* Wf   = (const float*)d_in[20];
    const float* bf   = (const float*)d_in[21];
    const int*   ei   = (const int*)d_in[22];
    const int*   batch= (const int*)d_in[23];
    float* out = (float*)d_out;

    // -------- workspace layout (~216 MB + 64 KB) --------
    float* ws = (float*)d_ws;
    size_t off = 0;
    float* q1    = ws + off;          off += (size_t)N_NODES * 64;
    uint* kvt1   = (uint*)(ws + off); off += (size_t)N_NODES * 64;
    float* s1    = ws + off;          off += (size_t)N_NODES * 64;   // skip -> h1
    float* q2    = ws + off;          off += (size_t)N_NODES * 16;
    uint* kvt2   = (uint*)(ws + off); off += (size_t)N_NODES * 16;
    float* s2    = ws + off;          off += (size_t)N_NODES * 16;
    int2* sorted = (int2*)(ws + off); off += (size_t)N_EDGES * 2;
    ushort* ep1  = (ushort*)(ws + off); off += (size_t)CHUNK_EDGE_CAP * 32;  // chunk-local
    ushort* ep2  = (ushort*)(ws + off); off += (size_t)N_EDGES * 8;          // global
    int* rowptr  = (int*)(ws + off);  off += N_NODES + 2;
    int* cursor  = (int*)(ws + off);  off += N_NODES;
    int* bsum    = (int*)(ws + off);  off += 512;
    // ---- contiguous zero block ----
    float* zerop = ws + off;
    int*   deg   = (int*)(ws + off);  off += N_NODES;
    float* sums  = ws + off;          off += (size_t)N_GRAPHS * 16;
    float* cnt   = ws + off;          off += N_GRAPHS;
    size_t zero_bytes = ((size_t)N_NODES + N_GRAPHS * 16 + N_GRAPHS) * sizeof(float);
    off = (off + 3) & ~(size_t)3;
    __half* Bpack = (__half*)(ws + off); off += 16384;   // 64 KB
    // alias: xh (fp16 x) on ep1 (dead before edge_mlp1)
    __half* xh = (__half*)ep1;

    hipMemsetAsync(zerop, 0, zero_bytes, stream);

    // -------- prep: x->fp16, W->fp16 fragment pack --------
    conv_x<<<6250, 256, 0, stream>>>(x, xh);
    prepack_W<<<16, 256, 0, stream>>>(Wq1, Wk1, Wv1, Ws1, Bpack);

    // -------- CSR build (shared by both layers) --------
    hist_kernel<<<(N_EDGES + 255) / 256, 256, 0, stream>>>(ei, deg);
    scan_block<<<NB_SCAN, 256, 0, stream>>>(deg, rowptr, bsum);
    scan_bsum<<<1, 512, 0, stream>>>(bsum);
    scan_add<<<NB_SCAN, 256, 0, stream>>>(rowptr, cursor, bsum);
    scatter_kernel<<<(N_EDGES + 255) / 256, 256, 0, stream>>>(ei, cursor, sorted);

    // -------- layer 1 node linear (MFMA) --------
    node_lin1_mfma<<<(N_NODES + 63) / 64, 256, 0, stream>>>(xh, bq1, bk1, bv1, bs1,
                                                            Bpack, q1, kvt1, s1);

    // -------- layer 1 (chunked: staged fused edge MLP -> aggregation) --------
    int mlp_blocks = (CHUNK_EDGE_CAP + 63) / 64;
    for (int c = 0; c < 4; ++c) {
        int n0 = c * NODES_PER_CHUNK;
        int n1 = (c + 1) * NODES_PER_CHUNK;
        if (n1 > N_NODES) n1 = N_NODES;
        edge_mlp1<<<mlp_blocks, 256, 0, stream>>>(sorted, rowptr, n0, n1, ea,
                                                  We1, We2, ep1, ep2);
        agg_l1<<<(NODES_PER_CHUNK + 3) / 4, 256, 0, stream>>>(sorted, rowptr, ep1,
                                                              q1, kvt1, s1, n0, n1);
    }

    // -------- layer 2 --------
    node_lin2<<<(N_NODES + 31) / 32, 256, 0, stream>>>(s1, Wq2, bq2, Wk2, bk2, Wv2, bv2,
                                                       Ws2, bs2, q2, kvt2, s2);
    agg_l2<<<(N_NODES + 3) / 4, 256, 0, stream>>>(sorted, rowptr, ep2, q2, kvt2,
                                                  s2, batch, sums, cnt);

    // -------- final fc --------
    final_fc<<<(N_GRAPHS + 255) / 256, 256, 0, stream>>>(sums, cnt, Wf, bf, out);
}